// Round 1
// baseline (3477.237 us; speedup 1.0000x reference)
//
#include <hip/hip_runtime.h>

// ---------------------------------------------------------------------------
// ATKT forward: embed -> xproj GEMM -> LSTM recurrence (MFMA, Whh in VGPRs)
//            -> mlp GEMM -> att -> attention-as-prefix-scan -> fc GEMM
// Shapes: B=64, S=512, HID=256, LSTM_IN=512, 4H=1024, ATTN=80, NC=1000
// ---------------------------------------------------------------------------

typedef short short8 __attribute__((ext_vector_type(8)));
typedef float f32x4 __attribute__((ext_vector_type(4)));

#define BS 32768            // B*S tokens
#define NC 1000

__device__ __forceinline__ short f2bf(float f) {
    unsigned u = __builtin_bit_cast(unsigned, f);
    unsigned r = (u + 0x7fffu + ((u >> 16) & 1u)) >> 16;   // RNE
    return (short)r;
}
__device__ __forceinline__ float bf2f(short s) {
    unsigned u = ((unsigned)(unsigned short)s) << 16;
    return __builtin_bit_cast(float, u);
}
__device__ __forceinline__ float sigm(float x) {
    return __builtin_amdgcn_rcpf(1.f + __expf(-x));
}
__device__ __forceinline__ float tanh_(float x) {
    float e = __expf(2.f * x);
    return 1.f - 2.f * __builtin_amdgcn_rcpf(e + 1.f);     // inf-safe: e=inf -> 1, e=0 -> -1
}

// ---------------------------------------------------------------------------
// prep: f32->bf16 weight casts (fc_W padded to 1024 rows, mlp_W to 128 rows,
// pad rows zeroed), bsum = bih+bhh.  Total 1,082,368 threads exactly.
// ---------------------------------------------------------------------------
__global__ void prep_kernel(const float* __restrict__ Wih, const float* __restrict__ fcW,
                            const float* __restrict__ mlpW, const float* __restrict__ bih,
                            const float* __restrict__ bhh,
                            short* __restrict__ wih_bf, short* __restrict__ fcw_bf,
                            short* __restrict__ mlpw_bf, float* __restrict__ bsum) {
    int i = blockIdx.x * 256 + threadIdx.x;
    if (i < 524288) {
        wih_bf[i] = f2bf(Wih[i]);
    } else if (i < 1048576) {
        int j = i - 524288;                 // fcw padded 1024x512
        int r = j >> 9;
        fcw_bf[j] = (r < NC) ? f2bf(fcW[j]) : (short)0;
    } else if (i < 1081344) {
        int j = i - 1048576;                // mlpw padded 128x256
        int r = j >> 8;
        mlpw_bf[j] = (r < 80) ? f2bf(mlpW[j]) : (short)0;
    } else {
        int j = i - 1081344;                // 1024 biases
        bsum[j] = bih[j] + bhh[j];
    }
}

// ---------------------------------------------------------------------------
// embed: sa_emb = answer==1 ? [se, ae] : [ae, se]; f32 to output #2, bf16 to ws.
// One block per token, 128 threads x float4.
// ---------------------------------------------------------------------------
__global__ void embed_kernel(const int* __restrict__ skill, const int* __restrict__ answer,
                             const float* __restrict__ se, const float* __restrict__ ae,
                             float* __restrict__ sa_out, short* __restrict__ sa_bf) {
    int token = blockIdx.x;
    int sk = skill[token], an = answer[token];
    const float* first  = (an == 1) ? (se + (size_t)sk * 256) : (ae + (size_t)an * 256);
    const float* second = (an == 1) ? (ae + (size_t)an * 256) : (se + (size_t)sk * 256);
    int j = threadIdx.x * 4;
    const float* src = (j < 256) ? (first + j) : (second + (j - 256));
    float4 v = *(const float4*)src;
    *(float4*)(sa_out + (size_t)token * 512 + j) = v;
    short4 s;
    s.x = f2bf(v.x); s.y = f2bf(v.y); s.z = f2bf(v.z); s.w = f2bf(v.w);
    *(short4*)(sa_bf + (size_t)token * 512 + j) = s;
}

// ---------------------------------------------------------------------------
// Generic MFMA bf16 GEMM: C[m,n] = A[m,:].W[n,:] (+bias[n]) [+sigmoid]
// A: M x K bf16 row-major, W: Npad x K bf16 row-major. WG tile 128x128,
// 4 waves in 2x2, each wave 64x64 = 4x4 tiles of 16x16x32. Direct global
// fragment loads (no LDS). grid = (M/128, Npad/128).
// Fragment layouts (HW-verified per guide):
//   A: A[m=lane&15][k=(lane>>4)*8+j]; B: B[k][n=lane&15], k=(lane>>4)*8+j
//   D: D[row=(lane>>4)*4+reg][col=lane&15]
// ---------------------------------------------------------------------------
__global__ __launch_bounds__(256) void gemm_kernel(
        const short* __restrict__ A, const short* __restrict__ Bw,
        const float* __restrict__ bias, float* __restrict__ C,
        int K, int ldC, int Nstore, int epi) {
    int bm = blockIdx.x * 128, bn = blockIdx.y * 128;
    int tid = threadIdx.x, wv = tid >> 6, lane = tid & 63;
    int quad = lane >> 4, l16 = lane & 15;
    int wm = (wv & 1) * 64, wn = (wv >> 1) * 64;

    const short* Abase = A + (size_t)(bm + wm + l16) * K + quad * 8;
    const short* Bbase = Bw + (size_t)(bn + wn + l16) * K + quad * 8;

    f32x4 acc[4][4] = {};
    for (int kk = 0; kk < K; kk += 32) {
        short8 a[4], b[4];
#pragma unroll
        for (int i = 0; i < 4; i++) a[i] = *(const short8*)(Abase + (size_t)i * 16 * K + kk);
#pragma unroll
        for (int j = 0; j < 4; j++) b[j] = *(const short8*)(Bbase + (size_t)j * 16 * K + kk);
#pragma unroll
        for (int i = 0; i < 4; i++)
#pragma unroll
            for (int j = 0; j < 4; j++)
                acc[i][j] = __builtin_amdgcn_mfma_f32_16x16x32_bf16(a[i], b[j], acc[i][j], 0, 0, 0);
    }
#pragma unroll
    for (int j = 0; j < 4; j++) {
        int col = bn + wn + j * 16 + l16;
        float bv = (bias && col < Nstore) ? bias[col] : 0.f;
        if (col >= Nstore) continue;
#pragma unroll
        for (int i = 0; i < 4; i++) {
            int row0 = bm + wm + i * 16 + quad * 4;
#pragma unroll
            for (int r = 0; r < 4; r++) {
                float v = acc[i][j][r] + bv;
                if (epi == 1) v = sigm(-(-v));   // sigmoid epilogue
                C[(size_t)(row0 + r) * ldC + col] = v;
            }
        }
    }
}

// ---------------------------------------------------------------------------
// LSTM recurrence. 4 WGs (one per 16-batch group) x 1024 threads (16 waves).
// Wave w owns hidden cols [w*16, w*16+16) across all 4 gates (i,f,g,o at
// n, n+256, n+512, n+768). Whh bf16 B-fragments pre-loaded into 128 VGPRs
// and reused for all 512 steps (zero Whh traffic in loop). h ping-pongs in
// LDS (row pad +8 bf16 -> +4 banks/row). xproj prefetched one step ahead
// and used as the MFMA C operand.
// ---------------------------------------------------------------------------
__global__ __launch_bounds__(1024, 4) void lstm_kernel(
        const float* __restrict__ xproj,   // [b*512+t][1024] f32
        const float* __restrict__ Whh,     // [1024][256] f32
        short* __restrict__ outH) {        // [b*512+t][256] bf16
    int g = blockIdx.x;                    // batch group 0..3
    int tid = threadIdx.x, wv = tid >> 6, lane = tid & 63;
    int quad = lane >> 4, l16 = lane & 15;
    int col = wv * 16 + l16;               // hidden column owned by this lane

    // --- preload Whh fragments: B[k][n] = Whh[n][k], n = gi*256 + col ---
    short8 fb[4][8];
#pragma unroll
    for (int gi = 0; gi < 4; gi++) {
#pragma unroll
        for (int kk = 0; kk < 8; kk++) {
            const float* p = Whh + (size_t)(gi * 256 + col) * 256 + kk * 32 + quad * 8;
            float4 x0 = *(const float4*)p;
            float4 x1 = *(const float4*)(p + 4);
            short8 s;
            s[0] = f2bf(x0.x); s[1] = f2bf(x0.y); s[2] = f2bf(x0.z); s[3] = f2bf(x0.w);
            s[4] = f2bf(x1.x); s[5] = f2bf(x1.y); s[6] = f2bf(x1.z); s[7] = f2bf(x1.w);
            fb[gi][kk] = s;
        }
    }

    __shared__ short hbuf[2][16][264];     // 16 batch rows x 256 (+8 pad) bf16, ping-pong
    for (int i = tid; i < 2 * 16 * 264; i += 1024) ((short*)hbuf)[i] = 0;

    float c[4] = {0.f, 0.f, 0.f, 0.f};     // cell state, rows m=quad*4+r

    size_t xbase[4], obase[4];
#pragma unroll
    for (int r = 0; r < 4; r++) {
        int b = g * 16 + quad * 4 + r;
        xbase[r] = (size_t)b * 512 * 1024 + col;   // + t*1024 + gi*256
        obase[r] = (size_t)b * 512 * 256 + col;    // + t*256
    }

    float xp[4][4];                        // [gate][row] prefetched xproj for step t
#pragma unroll
    for (int gi = 0; gi < 4; gi++)
#pragma unroll
        for (int r = 0; r < 4; r++)
            xp[gi][r] = xproj[xbase[r] + gi * 256];

    __syncthreads();

    for (int t = 0; t < 512; t++) {
        int cur = t & 1;
        // A fragments: h group (16 x 256) from LDS
        short8 a[8];
#pragma unroll
        for (int kk = 0; kk < 8; kk++)
            a[kk] = *(const short8*)&hbuf[cur][l16][kk * 32 + quad * 8];

        // prefetch next step's xproj while MFMA runs
        int tn = (t < 511) ? t + 1 : t;
        float xpn[4][4];
#pragma unroll
        for (int gi = 0; gi < 4; gi++)
#pragma unroll
            for (int r = 0; r < 4; r++)
                xpn[gi][r] = xproj[xbase[r] + (size_t)tn * 1024 + gi * 256];

        f32x4 acc[4];
#pragma unroll
        for (int gi = 0; gi < 4; gi++) {
            acc[gi][0] = xp[gi][0]; acc[gi][1] = xp[gi][1];
            acc[gi][2] = xp[gi][2]; acc[gi][3] = xp[gi][3];
        }
#pragma unroll
        for (int kk = 0; kk < 8; kk++)
#pragma unroll
            for (int gi = 0; gi < 4; gi++)
                acc[gi] = __builtin_amdgcn_mfma_f32_16x16x32_bf16(a[kk], fb[gi][kk], acc[gi], 0, 0, 0);

#pragma unroll
        for (int r = 0; r < 4; r++) {
            float iv = sigm(acc[0][r]);
            float fv = sigm(acc[1][r]);
            float gv = tanh_(acc[2][r]);
            float ov = sigm(acc[3][r]);
            c[r] = fv * c[r] + iv * gv;
            float h = ov * tanh_(c[r]);
            short hb = f2bf(h);
            hbuf[cur ^ 1][quad * 4 + r][col] = hb;
            outH[obase[r] + (size_t)t * 256] = hb;
        }
#pragma unroll
        for (int gi = 0; gi < 4; gi++)
#pragma unroll
            for (int r = 0; r < 4; r++)
                xp[gi][r] = xpn[gi][r];
        __syncthreads();
    }
}

// ---------------------------------------------------------------------------
// att[m] = sum_d tanh(mlpout[m,d]) * simW[d]   (mlp_b already added in GEMM)
// ---------------------------------------------------------------------------
__global__ void att_kernel(const float* __restrict__ mlpout, const float* __restrict__ simW,
                           float* __restrict__ att) {
    int m = blockIdx.x * 256 + threadIdx.x;
    float s = 0.f;
#pragma unroll
    for (int d = 0; d < 80; d += 4) {
        float4 v = *(const float4*)(mlpout + (size_t)m * 80 + d);
        float4 w = *(const float4*)(simW + d);
        s += tanh_(v.x) * w.x + tanh_(v.y) * w.y + tanh_(v.z) * w.z + tanh_(v.w) * w.w;
    }
    att[m] = s;
}

// ---------------------------------------------------------------------------
// Attention as prefix scan (exact rewrite of masked-softmax @ out + cumsum):
//   w_i = exp(att[b,i]);  S_i = sum_{j<=i} w_j*out_j;  W_i = sum_{j<=i} w_j
//   attn_out_i = S_i/W_i; attn_cum_1_i = sum_{i'<i} attn_out_{i'}
// Writes final = [attn_cum_1 | out] as bf16. One WG per batch element.
// ---------------------------------------------------------------------------
__global__ __launch_bounds__(256) void scan_kernel(const float* __restrict__ att,
                                                   const short* __restrict__ outH,
                                                   short* __restrict__ finalB) {
    int b = blockIdx.x, d = threadIdx.x;
    __shared__ float w_s[512];
    for (int i = d; i < 512; i += 256) w_s[i] = __expf(att[(size_t)b * 512 + i]);
    __syncthreads();

    float S = 0.f, W = 0.f, C = 0.f;
    const short* op = outH + (size_t)b * 512 * 256 + d;
    short* fp = finalB + (size_t)b * 512 * 512 + d;
    for (int i = 0; i < 512; i++) {
        float w = w_s[i];
        float ov = bf2f(op[(size_t)i * 256]);
        S += w * ov;
        W += w;
        float ao = S * __builtin_amdgcn_rcpf(W);
        fp[(size_t)i * 512]       = f2bf(C);    // exclusive cumsum
        fp[(size_t)i * 512 + 256] = f2bf(ov);   // out copy
        C += ao;
    }
}

// ---------------------------------------------------------------------------
extern "C" void kernel_launch(void* const* d_in, const int* in_sizes, int n_in,
                              void* d_out, int out_size, void* d_ws, size_t ws_size,
                              hipStream_t stream) {
    const int*   skill      = (const int*)d_in[0];
    const int*   answer     = (const int*)d_in[1];
    const float* skill_emb  = (const float*)d_in[2];
    const float* answer_emb = (const float*)d_in[3];
    const float* Wih        = (const float*)d_in[4];
    const float* Whh        = (const float*)d_in[5];
    const float* bih        = (const float*)d_in[6];
    const float* bhh        = (const float*)d_in[7];
    const float* mlp_W      = (const float*)d_in[8];
    const float* mlp_b      = (const float*)d_in[9];
    const float* sim_W      = (const float*)d_in[10];
    const float* fc_W       = (const float*)d_in[11];
    const float* fc_b       = (const float*)d_in[12];

    float* res    = (float*)d_out;               // [32768][1000]
    float* sa_out = res + (size_t)BS * NC;       // [32768][512]

    char* ws = (char*)d_ws;
    short* sa_bf   = (short*)(ws);               // 33,554,432 B
    short* outH    = (short*)(ws + 33554432);    // 16,777,216
    short* finalB  = (short*)(ws + 50331648);    // 33,554,432
    short* wih_bf  = (short*)(ws + 83886080);    //  1,048,576
    short* fcw_bf  = (short*)(ws + 84934656);    //  1,048,576 (padded 1024 rows)
    short* mlpw_bf = (short*)(ws + 85983232);    //     65,536 (padded 128 rows)
    float* bsum    = (float*)(ws + 86048768);    //      4,096
    float* att     = (float*)(ws + 86052864);    //    131,072
    float* mlpout  = (float*)(ws + 86183936);    // 10,485,760
    float* xproj   = (float*)(ws + 96669696);    // 134,217,728  (total ~231 MB)

    hipLaunchKernelGGL(prep_kernel, dim3(4228), dim3(256), 0, stream,
                       Wih, fc_W, mlp_W, bih, bhh, wih_bf, fcw_bf, mlpw_bf, bsum);
    hipLaunchKernelGGL(embed_kernel, dim3(BS), dim3(128), 0, stream,
                       skill, answer, skill_emb, answer_emb, sa_out, sa_bf);
    // xproj = sa @ Wih^T + (bih+bhh)
    hipLaunchKernelGGL(gemm_kernel, dim3(256, 8), dim3(256), 0, stream,
                       sa_bf, wih_bf, bsum, xproj, 512, 1024, 1024, 0);
    hipLaunchKernelGGL(lstm_kernel, dim3(4), dim3(1024), 0, stream, xproj, Whh, outH);
    // mlpout = out @ mlp_W^T + mlp_b   (Npad=128, store 80)
    hipLaunchKernelGGL(gemm_kernel, dim3(256, 1), dim3(256), 0, stream,
                       outH, mlpw_bf, mlp_b, mlpout, 256, 80, 80, 0);
    hipLaunchKernelGGL(att_kernel, dim3(128), dim3(256), 0, stream, mlpout, sim_W, att);
    hipLaunchKernelGGL(scan_kernel, dim3(64), dim3(256), 0, stream, att, outH, finalB);
    // res = sigmoid(final @ fc_W^T + fc_b)
    hipLaunchKernelGGL(gemm_kernel, dim3(256, 8), dim3(256), 0, stream,
                       finalB, fcw_bf, fc_b, res, 512, 1000, 1000, 1);
}

// Round 3
// 2032.606 us; speedup vs baseline: 1.7107x; 1.7107x over previous
//
#include <hip/hip_runtime.h>

// ---------------------------------------------------------------------------
// ATKT forward, all-f16 MFMA pipeline.
//   prep  -> casts + bias/qvec precompute
//   embed -> sa_emb (f32 out) + fused gather row index ridx
//   tgemm -> T tables: T1=se@Wl^T+q0, T0=se@Wr^T+q1, permuted f16 store
//   lstm  -> 4 WGs x 8 waves; Whh f16: 46 frag/thread VGPR + 18 frag/wave LDS
//   mlp gemm -> att -> scan (softmax-as-prefix-scan) -> fc gemm (sigmoid)
// R3 fix: tgemm b[j] was missing the j*16*ldB n-tile offset (all n-tiles read
// tile 0's weights -> absmax 0.59). One-line fix.
// ---------------------------------------------------------------------------

typedef _Float16 half8 __attribute__((ext_vector_type(8)));
typedef float f32x4 __attribute__((ext_vector_type(4)));

#define BS 32768
#define NC 1000

__device__ __forceinline__ float sigm(float x) {
    return __builtin_amdgcn_rcpf(1.f + __expf(-x));
}
__device__ __forceinline__ float tanh_(float x) {
    float e = __expf(2.f * x);
    return 1.f - 2.f * __builtin_amdgcn_rcpf(e + 1.f);
}

// ---------------------------------------------------------------------------
// prep: f32->f16 casts, bsum=bih+bhh, qvec[0]=ae[1]@Wr^T+bsum, qvec[1]=ae[0]@Wl^T+bsum
// ---------------------------------------------------------------------------
__global__ void prep_kernel(const float* __restrict__ Wih, const float* __restrict__ fcW,
                            const float* __restrict__ mlpW, const float* __restrict__ se,
                            const float* __restrict__ ae, const float* __restrict__ bih,
                            const float* __restrict__ bhh,
                            _Float16* __restrict__ wih16, _Float16* __restrict__ fcw16,
                            _Float16* __restrict__ mlpw16, _Float16* __restrict__ se16,
                            float* __restrict__ bsum, float* __restrict__ qvec) {
    int i = blockIdx.x * 256 + threadIdx.x;
    if (i < 524288) {
        wih16[i] = (_Float16)Wih[i];
    } else if (i < 1048576) {
        int j = i - 524288;                 // fcw padded 1024x512
        int r = j >> 9;
        fcw16[j] = (r < NC) ? (_Float16)fcW[j] : (_Float16)0.f;
    } else if (i < 1081344) {
        int j = i - 1048576;                // mlpw padded 128x256
        int r = j >> 8;
        mlpw16[j] = (r < 80) ? (_Float16)mlpW[j] : (_Float16)0.f;
    } else if (i < 1337600) {
        int j = i - 1081344;                // se 1001x256
        se16[j] = (_Float16)se[j];
    } else if (i < 1338624) {
        int j = i - 1337600;
        bsum[j] = bih[j] + bhh[j];
    } else if (i < 1340672) {
        int j = i - 1338624;                // qvec 2x1024
        int which = j >> 10, col = j & 1023;
        int aerow = (which == 0) ? 1 : 0;   // T1 uses ae[1]@Wr; T0 uses ae[0]@Wl
        int koff  = (which == 0) ? 256 : 0;
        float s = 0.f;
        for (int k = 0; k < 256; k++)
            s += ae[aerow * 256 + k] * Wih[(size_t)col * 512 + koff + k];
        qvec[j] = s + bih[col] + bhh[col];
    }
}

// ---------------------------------------------------------------------------
// embed: sa_emb f32 output + ridx (row into T table: ans==1 ? sk : 1024+sk)
// ---------------------------------------------------------------------------
__global__ void embed_kernel(const int* __restrict__ skill, const int* __restrict__ answer,
                             const float* __restrict__ se, const float* __restrict__ ae,
                             float* __restrict__ sa_out, int* __restrict__ ridx) {
    int token = blockIdx.x;
    int sk = skill[token], an = answer[token];
    const float* first  = (an == 1) ? (se + (size_t)sk * 256) : (ae + (size_t)an * 256);
    const float* second = (an == 1) ? (ae + (size_t)an * 256) : (se + (size_t)sk * 256);
    int j = threadIdx.x * 4;
    const float* src = (j < 256) ? (first + j) : (second + (j - 256));
    float4 v = *(const float4*)src;
    *(float4*)(sa_out + (size_t)token * 512 + j) = v;
    if (threadIdx.x == 0) ridx[token] = (an == 1) ? sk : (1024 + sk);
}

// ---------------------------------------------------------------------------
// tgemm: T tables (2048x1024), A=se16 (row-clamped), B=wih16 (ldB=512,+koff),
// epilogue adds qvec and stores f16 permuted: T_sw[row*1024 + w*128+l16*8+v],
// where col = (v>>1)*256 + 32w + (v&1)*16 + l16.
// ---------------------------------------------------------------------------
__global__ __launch_bounds__(256) void tgemm_kernel(
        const _Float16* __restrict__ A, const _Float16* __restrict__ Bw,
        const float* __restrict__ qvec, _Float16* __restrict__ Tsw) {
    int bm = blockIdx.x * 128, bn = blockIdx.y * 128;
    int which = bm >> 10;
    int mbase = bm & 1023;
    int koff = which ? 256 : 0;
    int tid = threadIdx.x, wv = tid >> 6, lane = tid & 63;
    int quad = lane >> 4, l16 = lane & 15;
    int wm = (wv & 1) * 64, wn = (wv >> 1) * 64;

    int arow[4];
#pragma unroll
    for (int i = 0; i < 4; i++) {
        int r = mbase + wm + i * 16 + l16;
        arow[i] = (r > 1000) ? 1000 : r;
    }
    const _Float16* Bbase = Bw + (size_t)(bn + wn + l16) * 512 + koff + quad * 8;

    f32x4 acc[4][4] = {};
    for (int kk = 0; kk < 256; kk += 32) {
        half8 a[4], b[4];
#pragma unroll
        for (int i = 0; i < 4; i++)
            a[i] = *(const half8*)(A + (size_t)arow[i] * 256 + quad * 8 + kk);
#pragma unroll
        for (int j = 0; j < 4; j++)
            b[j] = *(const half8*)(Bbase + (size_t)j * 16 * 512 + kk);   // R3 FIX
#pragma unroll
        for (int i = 0; i < 4; i++)
#pragma unroll
            for (int j = 0; j < 4; j++)
                acc[i][j] = __builtin_amdgcn_mfma_f32_16x16x32_f16(a[i], b[j], acc[i][j], 0, 0, 0);
    }
#pragma unroll
    for (int j = 0; j < 4; j++) {
        int col = bn + wn + j * 16 + l16;
        float qv = qvec[which * 1024 + col];
        int perm = ((col & 255) >> 5) * 128 + (col & 15) * 8 + ((col >> 8) * 2 + ((col >> 4) & 1));
#pragma unroll
        for (int i = 0; i < 4; i++) {
            int row = mbase + wm + i * 16 + quad * 4;
#pragma unroll
            for (int r = 0; r < 4; r++) {
                if (row + r > 1000) continue;
                Tsw[(size_t)((which << 10) + row + r) * 1024 + perm] = (_Float16)(acc[i][j][r] + qv);
            }
        }
    }
}

// ---------------------------------------------------------------------------
// LSTM. 4 WGs x 512 threads (8 waves, 2/SIMD, <=256 VGPR).
// Wave w owns hidden cols [32w,32w+32): gate cols (v>>1)*256 + 32w + (v&1)*16 + l16.
// Whh f16 frags: (v,k) k<5 or (k==5,v<6) in VGPRs (46), rest in LDS (18/wave).
// h in LDS stored in A-fragment order (contiguous ds_read_b128, conflict-free).
// Gate pre-acts init from T-table gather (prefetched 1 step; indices 2 steps).
// ---------------------------------------------------------------------------
__global__ __launch_bounds__(512, 2) void lstm_kernel(
        const float* __restrict__ Whh,          // [1024][256] f32
        const _Float16* __restrict__ Tsw,       // [2048][1024] f16 permuted
        const int* __restrict__ ridxArr,        // [B*S]
        _Float16* __restrict__ outH) {          // [b*512+t][256] f16
    int g16 = blockIdx.x;
    int tid = threadIdx.x, wv = tid >> 6, lane = tid & 63;
    int quad = lane >> 4, l16 = lane & 15;

    extern __shared__ char smem[];
    _Float16* ldsB = (_Float16*)smem;                  // 8 waves * 18 frags * 512 f16
    _Float16* hA   = (_Float16*)(smem + 147456);       // 8 KB, A-frag order

    // ---- fill Whh fragments (f32 -> f16) ----
    half8 rB[46];
#pragma unroll
    for (int v = 0; v < 8; v++) {
#pragma unroll
        for (int k = 0; k < 8; k++) {
            int col = (v >> 1) * 256 + wv * 32 + (v & 1) * 16 + l16;
            const float* p = Whh + (size_t)col * 256 + k * 32 + quad * 8;
            float4 x0 = *(const float4*)p;
            float4 x1 = *(const float4*)(p + 4);
            half8 hb;
            hb[0] = (_Float16)x0.x; hb[1] = (_Float16)x0.y; hb[2] = (_Float16)x0.z; hb[3] = (_Float16)x0.w;
            hb[4] = (_Float16)x1.x; hb[5] = (_Float16)x1.y; hb[6] = (_Float16)x1.z; hb[7] = (_Float16)x1.w;
            if (k < 5) rB[k * 8 + v] = hb;
            else if (k == 5 && v < 6) rB[40 + v] = hb;
            else {
                int f = (k == 5) ? (v - 6) : ((k == 6) ? (2 + v) : (10 + v));
                *(half8*)(ldsB + ((size_t)wv * 18 + f) * 512 + lane * 8) = hb;
            }
        }
    }
    // zero h
    ((float4*)hA)[tid] = float4{0.f, 0.f, 0.f, 0.f};

    float c[2][4] = {};
    int tb[4];
    _Float16* po[4];
#pragma unroll
    for (int r = 0; r < 4; r++) {
        int b = g16 * 16 + quad * 4 + r;
        tb[r] = b * 512;
        po[r] = outH + (size_t)b * 512 * 256 + wv * 32 + l16;
    }
    // prologue gathers
    half8 Tcur[4];
    unsigned ridxA[4];
#pragma unroll
    for (int r = 0; r < 4; r++) {
        int r0 = ridxArr[tb[r]];
        Tcur[r] = *(const half8*)(Tsw + (size_t)r0 * 1024 + wv * 128 + l16 * 8);
        ridxA[r] = ridxArr[tb[r] + 1];
    }
    __syncthreads();

    for (int t = 0; t < 512; t++) {
        // prefetch next T rows + indices two ahead
        half8 Tnx[4];
        unsigned ridxB[4];
        int tn2 = (t + 2 < 512) ? t + 2 : 511;
#pragma unroll
        for (int r = 0; r < 4; r++)
            Tnx[r] = *(const half8*)(Tsw + (size_t)ridxA[r] * 1024 + wv * 128 + l16 * 8);
#pragma unroll
        for (int r = 0; r < 4; r++) ridxB[r] = ridxArr[tb[r] + tn2];

        f32x4 acc[8];
#pragma unroll
        for (int v = 0; v < 8; v++) acc[v] = f32x4{0.f, 0.f, 0.f, 0.f};

#pragma unroll
        for (int k = 0; k < 8; k++) {
            half8 av = *(const half8*)(hA + k * 512 + lane * 8);
#pragma unroll
            for (int v = 0; v < 8; v++) {
                half8 bv;
                if (k < 5) bv = rB[k * 8 + v];
                else if (k == 5 && v < 6) bv = rB[40 + v];
                else {
                    int f = (k == 5) ? (v - 6) : ((k == 6) ? (2 + v) : (10 + v));
                    bv = *(const half8*)(ldsB + ((size_t)wv * 18 + f) * 512 + lane * 8);
                }
                acc[v] = __builtin_amdgcn_mfma_f32_16x16x32_f16(av, bv, acc[v], 0, 0, 0);
            }
        }

        // elementwise gate update
        _Float16 hw[2][4];
#pragma unroll
        for (int j = 0; j < 2; j++) {
#pragma unroll
            for (int r = 0; r < 4; r++) {
                float ii = sigm(acc[0 + j][r] + (float)Tcur[r][0 + j]);
                float ff = sigm(acc[2 + j][r] + (float)Tcur[r][2 + j]);
                float gg = tanh_(acc[4 + j][r] + (float)Tcur[r][4 + j]);
                float oo = sigm(acc[6 + j][r] + (float)Tcur[r][6 + j]);
                c[j][r] = ff * c[j][r] + ii * gg;
                float h = oo * tanh_(c[j][r]);
                _Float16 hf = (_Float16)h;
                hw[j][r] = hf;
                po[r][j * 16] = hf;            // global outH store
            }
        }
        __syncthreads();   // all waves done reading hA for step t
        // write new h into A-frag layout: elem offset = wv*512 + (2j+(l16>>3))*128 + b*8 + (l16&7)
#pragma unroll
        for (int j = 0; j < 2; j++) {
#pragma unroll
            for (int r = 0; r < 4; r++)
                hA[wv * 512 + (2 * j + (l16 >> 3)) * 128 + (quad * 4 + r) * 8 + (l16 & 7)] = hw[j][r];
        }
        __syncthreads();   // writes visible for step t+1

#pragma unroll
        for (int r = 0; r < 4; r++) {
            Tcur[r] = Tnx[r];
            ridxA[r] = ridxB[r];
            po[r] += 256;
        }
    }
}

// ---------------------------------------------------------------------------
// Generic f16 MFMA GEMM: C = A @ Bw^T (+bias), epi 1 = sigmoid. Direct-global.
// ---------------------------------------------------------------------------
__global__ __launch_bounds__(256) void gemm_f16(
        const _Float16* __restrict__ A, const _Float16* __restrict__ Bw,
        const float* __restrict__ bias, float* __restrict__ C,
        int K, int ldC, int Nstore, int epi) {
    int bm = blockIdx.x * 128, bn = blockIdx.y * 128;
    int tid = threadIdx.x, wv = tid >> 6, lane = tid & 63;
    int quad = lane >> 4, l16 = lane & 15;
    int wm = (wv & 1) * 64, wn = (wv >> 1) * 64;

    const _Float16* Abase = A + (size_t)(bm + wm + l16) * K + quad * 8;
    const _Float16* Bbase = Bw + (size_t)(bn + wn + l16) * K + quad * 8;

    f32x4 acc[4][4] = {};
    for (int kk = 0; kk < K; kk += 32) {
        half8 a[4], b[4];
#pragma unroll
        for (int i = 0; i < 4; i++) a[i] = *(const half8*)(Abase + (size_t)i * 16 * K + kk);
#pragma unroll
        for (int j = 0; j < 4; j++) b[j] = *(const half8*)(Bbase + (size_t)j * 16 * K + kk);
#pragma unroll
        for (int i = 0; i < 4; i++)
#pragma unroll
            for (int j = 0; j < 4; j++)
                acc[i][j] = __builtin_amdgcn_mfma_f32_16x16x32_f16(a[i], b[j], acc[i][j], 0, 0, 0);
    }
#pragma unroll
    for (int j = 0; j < 4; j++) {
        int col = bn + wn + j * 16 + l16;
        if (col >= Nstore) continue;
        float bv = bias ? bias[col] : 0.f;
#pragma unroll
        for (int i = 0; i < 4; i++) {
            int row0 = bm + wm + i * 16 + quad * 4;
#pragma unroll
            for (int r = 0; r < 4; r++) {
                float v = acc[i][j][r] + bv;
                if (epi == 1) v = sigm(v);
                C[(size_t)(row0 + r) * ldC + col] = v;
            }
        }
    }
}

// ---------------------------------------------------------------------------
__global__ void att_kernel(const float* __restrict__ mlpout, const float* __restrict__ simW,
                           float* __restrict__ att) {
    int m = blockIdx.x * 256 + threadIdx.x;
    float s = 0.f;
#pragma unroll
    for (int d = 0; d < 80; d += 4) {
        float4 v = *(const float4*)(mlpout + (size_t)m * 80 + d);
        float4 w = *(const float4*)(simW + d);
        s += tanh_(v.x) * w.x + tanh_(v.y) * w.y + tanh_(v.z) * w.z + tanh_(v.w) * w.w;
    }
    att[m] = s;
}

// ---------------------------------------------------------------------------
// Attention as prefix scan; writes final = [attn_cum_1 | out] f16.
// ---------------------------------------------------------------------------
__global__ __launch_bounds__(256) void scan_kernel(const float* __restrict__ att,
                                                   const _Float16* __restrict__ outH,
                                                   _Float16* __restrict__ finalB) {
    int b = blockIdx.x, d = threadIdx.x;
    __shared__ float w_s[512];
    for (int i = d; i < 512; i += 256) w_s[i] = __expf(att[(size_t)b * 512 + i]);
    __syncthreads();

    float S = 0.f, W = 0.f, C = 0.f;
    const _Float16* op = outH + (size_t)b * 512 * 256 + d;
    _Float16* fp = finalB + (size_t)b * 512 * 512 + d;
    for (int i = 0; i < 512; i++) {
        float w = w_s[i];
        float ov = (float)op[(size_t)i * 256];
        S += w * ov;
        W += w;
        float ao = S * __builtin_amdgcn_rcpf(W);
        fp[(size_t)i * 512]       = (_Float16)C;
        fp[(size_t)i * 512 + 256] = (_Float16)ov;
        C += ao;
    }
}

// ---------------------------------------------------------------------------
extern "C" void kernel_launch(void* const* d_in, const int* in_sizes, int n_in,
                              void* d_out, int out_size, void* d_ws, size_t ws_size,
                              hipStream_t stream) {
    const int*   skill      = (const int*)d_in[0];
    const int*   answer     = (const int*)d_in[1];
    const float* skill_emb  = (const float*)d_in[2];
    const float* answer_emb = (const float*)d_in[3];
    const float* Wih        = (const float*)d_in[4];
    const float* Whh        = (const float*)d_in[5];
    const float* bih        = (const float*)d_in[6];
    const float* bhh        = (const float*)d_in[7];
    const float* mlp_W      = (const float*)d_in[8];
    const float* mlp_b      = (const float*)d_in[9];
    const float* sim_W      = (const float*)d_in[10];
    const float* fc_W       = (const float*)d_in[11];
    const float* fc_b       = (const float*)d_in[12];

    float* res    = (float*)d_out;               // [32768][1000]
    float* sa_out = res + (size_t)BS * NC;       // [32768][512]

    char* ws = (char*)d_ws;
    _Float16* outH   = (_Float16*)(ws);                 // 16,777,216 B
    _Float16* finalB = (_Float16*)(ws + 16777216);      // 33,554,432
    _Float16* wih16  = (_Float16*)(ws + 50331648);      //  1,048,576
    _Float16* fcw16  = (_Float16*)(ws + 51380224);      //  1,048,576
    _Float16* mlpw16 = (_Float16*)(ws + 52428800);      //     65,536
    _Float16* se16   = (_Float16*)(ws + 52494336);      //    524,288 (512,512 used)
    float*    bsum   = (float*)(ws + 53018624);         //      4,096
    float*    qvec   = (float*)(ws + 53022720);         //      8,192
    float*    att    = (float*)(ws + 53030912);         //    131,072
    float*    mlpout = (float*)(ws + 53161984);         // 10,485,760
    _Float16* Tsw    = (_Float16*)(ws + 63647744);      //  4,194,304
    int*      ridx   = (int*)(ws + 67842048);           //    131,072

    (void)bsum; (void)in_sizes; (void)n_in; (void)out_size; (void)ws_size;

    hipLaunchKernelGGL(prep_kernel, dim3(5238), dim3(256), 0, stream,
                       Wih, fc_W, mlp_W, skill_emb, answer_emb, bih, bhh,
                       wih16, fcw16, mlpw16, se16, bsum, qvec);
    hipLaunchKernelGGL(embed_kernel, dim3(BS), dim3(128), 0, stream,
                       skill, answer, skill_emb, answer_emb, sa_out, ridx);
    hipLaunchKernelGGL(tgemm_kernel, dim3(16, 8), dim3(256), 0, stream,
                       se16, wih16, qvec, Tsw);

    hipFuncSetAttribute((const void*)lstm_kernel,
                        hipFuncAttributeMaxDynamicSharedMemorySize, 155648);
    hipLaunchKernelGGL(lstm_kernel, dim3(4), dim3(512), 155648, stream,
                       Whh, Tsw, ridx, outH);

    hipLaunchKernelGGL(gemm_f16, dim3(256, 1), dim3(256), 0, stream,
                       outH, mlpw16, mlp_b, mlpout, 256, 80, 80, 0);
    hipLaunchKernelGGL(att_kernel, dim3(128), dim3(256), 0, stream, mlpout, sim_W, att);
    hipLaunchKernelGGL(scan_kernel, dim3(64), dim3(256), 0, stream, att, outH, finalB);
    hipLaunchKernelGGL(gemm_f16, dim3(256, 8), dim3(256), 0, stream,
                       finalB, fcw16, fc_b, res, 512, 1000, 1000, 1);
}